// Round 1
// baseline (522.361 us; speedup 1.0000x reference)
//
#include <hip/hip_runtime.h>
#include <hip/hip_bf16.h>

#define N_NODES 50000
#define N_EDGES 1600000
#define IN_DIM 1024
#define HID 128
#define AGG_WAVES 6144          // 1536 blocks x 4 waves = 24 waves/CU at launch_bounds(256,6)

typedef __bf16 bf16x8 __attribute__((ext_vector_type(8)));
typedef float f32x4 __attribute__((ext_vector_type(4)));
typedef __bf16 bf16x4 __attribute__((ext_vector_type(4)));

// bf16-pair (packed in uint) -> 2 floats (features 2l = low, 2l+1 = high)
__device__ __forceinline__ float2 bf2f(unsigned u) {
    return make_float2(__uint_as_float(u << 16), __uint_as_float(u & 0xffff0000u));
}
__device__ __forceinline__ float lrelu(float v) { return v > 0.f ? v : 0.2f * v; }

// ---------------------------------------------------------------- prep: zero deg/out + W^T->bf16
__global__ void prep_kernel(const float* __restrict__ W, __bf16* __restrict__ wt,
                            int* __restrict__ deg, float* __restrict__ out, int out_n) {
    int i = blockIdx.x * 256 + threadIdx.x;       // grid covers 131072
    if (i < N_NODES) deg[i] = 0;
    if (i < out_n) out[i] = 0.0f;
    if (i < HID * IN_DIM) {
        int n = i >> 10, k = i & 1023;
        wt[i] = (__bf16)W[(size_t)k * HID + n];
    }
}

// ---------------------------------------------------------------- GEMM h = x @ W (bf16 MFMA)
// BM=64 x BN=128 (full HID), BK=32, 782 blocks. Double-buffered LDS, one barrier
// per k-iter, register prefetch of next tile. Fused att epilogue now ALSO emits
// pself = exp(lrelu(a_src+a_dst)) per row so aggregate never touches a_dst/exp.
__global__ __launch_bounds__(256) void gemm_kernel(const float* __restrict__ x,
                                                   const __bf16* __restrict__ wt,
                                                   __bf16* __restrict__ h2,
                                                   const float* __restrict__ att_s,
                                                   const float* __restrict__ att_d,
                                                   float* __restrict__ o_as,
                                                   float* __restrict__ o_ad,
                                                   float* __restrict__ o_ps) {
    __shared__ __bf16 xa[2][64][40];
    __shared__ __bf16 wb[2][128][40];
    const int t = threadIdx.x;
    const int m0 = blockIdx.x * 64;
    const int wid = t >> 6, lane = t & 63;
    const int lm = lane & 15, q8 = (lane >> 4) * 8;
    const int rw0 = wid * 16;

    float4 xs_reg[2];
    uint2  ws_reg[4];

    auto stage_regs = [&](int k0) {
#pragma unroll
        for (int l = 0; l < 2; ++l) {
            int f = t + l * 256;
            int row = f >> 3, kq = f & 7;
            int gr = m0 + row;
            float4 v = make_float4(0.f, 0.f, 0.f, 0.f);
            if (gr < N_NODES)
                v = *(const float4*)(x + (size_t)gr * IN_DIM + k0 + kq * 4);
            xs_reg[l] = v;
        }
#pragma unroll
        for (int l = 0; l < 4; ++l) {
            int f = t + l * 256;
            int n = f >> 3, c = f & 7;
            ws_reg[l] = *(const uint2*)(wt + (size_t)n * IN_DIM + k0 + c * 4);
        }
    };
    auto regs_to_lds = [&](int b) {
#pragma unroll
        for (int l = 0; l < 2; ++l) {
            int f = t + l * 256;
            int row = f >> 3, kq = f & 7;
            bf16x4 v;
            v[0] = (__bf16)xs_reg[l].x; v[1] = (__bf16)xs_reg[l].y;
            v[2] = (__bf16)xs_reg[l].z; v[3] = (__bf16)xs_reg[l].w;
            *(bf16x4*)&xa[b][row][kq * 4] = v;
        }
#pragma unroll
        for (int l = 0; l < 4; ++l) {
            int f = t + l * 256;
            int n = f >> 3, c = f & 7;
            *(uint2*)&wb[b][n][c * 4] = ws_reg[l];
        }
    };

    f32x4 acc[8] = {};
    stage_regs(0);
    regs_to_lds(0);
    __syncthreads();
    for (int it = 0; it < 32; ++it) {
        const int cur = it & 1;
        if (it + 1 < 32) stage_regs((it + 1) * 32);   // global loads in flight during MFMA
        bf16x8 af = *(const bf16x8*)&xa[cur][rw0 + lm][q8];
#pragma unroll
        for (int ct = 0; ct < 8; ++ct) {
            bf16x8 bfr = *(const bf16x8*)&wb[cur][ct * 16 + lm][q8];
            acc[ct] = __builtin_amdgcn_mfma_f32_16x16x32_bf16(af, bfr, acc[ct], 0, 0, 0);
        }
        if (it + 1 < 32) {
            regs_to_lds(cur ^ 1);     // write OTHER buffer: no read-write conflict
            __syncthreads();          // make writes visible for next iter's reads
        }
    }
    // epilogue: C/D layout col=lane&15, row=(lane>>4)*4+reg ; fused att dots
    const int quad = lane >> 4;
    float attsf[8], attdf[8];
#pragma unroll
    for (int ct = 0; ct < 8; ++ct) {
        attsf[ct] = att_s[ct * 16 + lm];
        attdf[ct] = att_d[ct * 16 + lm];
    }
#pragma unroll
    for (int reg = 0; reg < 4; ++reg) {
        int row = m0 + rw0 + quad * 4 + reg;
        float ps = 0.f, pd = 0.f;
#pragma unroll
        for (int ct = 0; ct < 8; ++ct) {
            float v = acc[ct][reg];
            ps = fmaf(v, attsf[ct], ps);
            pd = fmaf(v, attdf[ct], pd);
        }
#pragma unroll
        for (int o = 8; o; o >>= 1) {
            ps += __shfl_xor(ps, o);
            pd += __shfl_xor(pd, o);
        }
        if (row < N_NODES) {
            if (lm == 0) {
                o_as[row] = ps; o_ad[row] = pd;
                o_ps[row] = __expf(lrelu(ps + pd));   // self-loop weight, precomputed
            }
#pragma unroll
            for (int ct = 0; ct < 8; ++ct)
                h2[(size_t)row * HID + ct * 16 + lm] = (__bf16)acc[ct][reg];
        }
    }
}

// ---------------------------------------------------------------- CSR build
// hist counts in-degree only; slot assignment moved to scatter's atomic cursor
// (epos pass eliminated: -6.4MB write, -6.4MB read).
__global__ void hist_kernel(const int* __restrict__ ei, int* __restrict__ deg) {
    int e = blockIdx.x * 256 + threadIdx.x;
    if (e < N_EDGES) atomicAdd(&deg[ei[N_EDGES + e]], 1);
}

__global__ void scan1_kernel(const int* __restrict__ deg, int* __restrict__ bsum) {
    int b = blockIdx.x, t = threadIdx.x;
    int base = b * 1024 + t * 4;
    int s = 0;
#pragma unroll
    for (int j = 0; j < 4; ++j) {
        int idx = base + j;
        if (idx < N_NODES) s += deg[idx];
    }
    for (int o = 32; o; o >>= 1) s += __shfl_xor(s, o);
    __shared__ int wsum[4];
    int lane = t & 63, w = t >> 6;
    if (lane == 0) wsum[w] = s;
    __syncthreads();
    if (t == 0) bsum[b] = wsum[0] + wsum[1] + wsum[2] + wsum[3];
}

__global__ void scan2_kernel(const int* __restrict__ bsum, int* __restrict__ boff,
                             int* __restrict__ rowstart, int nb) {
    if (threadIdx.x == 0 && blockIdx.x == 0) {
        int run = 0;
        for (int i = 0; i < nb; ++i) { boff[i] = run; run += bsum[i]; }
        rowstart[N_NODES] = run;
    }
}

// also materializes cursor = rowstart copy for scatter's atomic slot claim
__global__ void scan3_kernel(const int* __restrict__ deg, const int* __restrict__ boff,
                             int* __restrict__ rowstart, int* __restrict__ cursor) {
    int b = blockIdx.x, t = threadIdx.x;
    int base = b * 1024 + t * 4;
    int v[4]; int s = 0;
#pragma unroll
    for (int j = 0; j < 4; ++j) {
        int idx = base + j;
        v[j] = (idx < N_NODES) ? deg[idx] : 0;
        s += v[j];
    }
    int lane = t & 63, w = t >> 6;
    int inc = s;
    for (int o = 1; o < 64; o <<= 1) {
        int u = __shfl_up(inc, o);
        if (lane >= o) inc += u;
    }
    __shared__ int wt[4];
    if (lane == 63) wt[w] = inc;
    __syncthreads();
    int woff = 0;
    for (int i = 0; i < w; ++i) woff += wt[i];
    int run = woff + inc - s + boff[b];
#pragma unroll
    for (int j = 0; j < 4; ++j) {
        int idx = base + j;
        if (idx < N_NODES) {
            rowstart[idx] = run;
            cursor[idx] = run;
            run += v[j];
        }
    }
}

// scatter: slot via atomic cursor (order within a row is irrelevant — commutative
// sum). Payload is (src, p_e) with p_e = exp(lrelu(a_src[s]+a_dst[d])) FULLY
// precomputed here, so the hot aggregate loop does zero transcendental work.
__global__ void scatter_kernel(const int* __restrict__ ei, int* __restrict__ cursor,
                               uint2* __restrict__ csrp, const float* __restrict__ a_src,
                               const float* __restrict__ a_dst) {
    int e = blockIdx.x * 256 + threadIdx.x;
    if (e >= N_EDGES) return;
    int s = ei[e], d = ei[N_EDGES + e];
    int slot = atomicAdd(&cursor[d], 1);
    float pe = __expf(lrelu(a_src[s] + a_dst[d]));
    uint2 v; v.x = (unsigned)s; v.y = __float_as_uint(pe);
    csrp[slot] = v;
}

// ---------------------------------------------------------------- aggregate+pool
// NEW GATHER SHAPE: 16 lanes x dwordx4 per h2 row -> 4 edges per wave VMEM instr
// (was 64 lanes x dword -> 1 edge). Quad q of the wave owns edge 4g+q of each
// group; ONE ds_bpermute pair distributes (src,pe) for 4 edges. Per-edge cost
// drops from {2 bpermute + 1 vmem} to {0.5 bpermute + 0.25 vmem}. Each lane
// accumulates features ql*8..ql*8+7; cross-quad shfl_xor(16/32) at node end
// also produces the softmax denominator from the already-broadcast pe values.
// Invalid lanes carry (0,0) so padded groups are weight-0 row-0 gathers.
__global__ __launch_bounds__(256, 6) void aggregate_kernel(
    const uint4* __restrict__ h2q, const float* __restrict__ pself_a,
    const int* __restrict__ rowstart, const uint2* __restrict__ csrp,
    const float* __restrict__ bias, const int* __restrict__ batch,
    float* __restrict__ out) {
    const int wid = threadIdx.x >> 6, lane = threadIdx.x & 63;
    const int w = blockIdx.x * 4 + wid;
    const int quad = lane >> 4, ql = lane & 15;
    const int vq = quad << 2;                 // bpermute byte offset within a group
    const int q = N_NODES / AGG_WAVES;
    const int r = N_NODES - q * AGG_WAVES;
    int n0 = w * q + (w < r ? w : r);
    int n1 = n0 + q + (w < r ? 1 : 0);

    // per-lane bias for features ql*8 .. ql*8+7 (loaded once, L1-resident)
    float bl[8];
    {
        const float4* b4 = (const float4*)bias;
        float4 x0 = b4[ql * 2], x1 = b4[ql * 2 + 1];
        bl[0] = x0.x; bl[1] = x0.y; bl[2] = x0.z; bl[3] = x0.w;
        bl[4] = x1.x; bl[5] = x1.y; bl[6] = x1.z; bl[7] = x1.w;
    }

    int gcur = -1;
    float m0 = 0.f, m1 = 0.f;
    for (int n = n0; n < n1; ++n) {
        int rs = rowstart[n], re = rowstart[n + 1];
        float psf = pself_a[n];
        // self row: same 4 cache lines for all quads (broadcast), weight only in quad 0
        uint4 sv = h2q[(size_t)n * 16 + ql];
        float w0 = (quad == 0) ? psf : 0.f;
        float a[8];
        {
            float2 f0 = bf2f(sv.x), f1 = bf2f(sv.y), f2 = bf2f(sv.z), f3 = bf2f(sv.w);
            a[0] = w0 * f0.x; a[1] = w0 * f0.y; a[2] = w0 * f1.x; a[3] = w0 * f1.y;
            a[4] = w0 * f2.x; a[5] = w0 * f2.y; a[6] = w0 * f3.x; a[7] = w0 * f3.y;
        }
        float pws = 0.f;                       // per-quad partial denom (excl. pself)
        for (int base = rs; base < re; base += 64) {
            int cnt = re - base; if (cnt > 64) cnt = 64;
            uint2 sp = make_uint2(0u, 0u);     // pe=0 for invalid lanes
            if (base + lane < re) sp = csrp[base + lane];
            int ngrp = (cnt + 3) >> 2;
            ngrp = (ngrp + 3) & ~3;            // multiple of 4 for the fixed unroll
            for (int g = 0; g < ngrp; g += 4) {
                uint4 uu[4]; float pw[4];
#pragma unroll
                for (int i = 0; i < 4; ++i) {
                    int bidx = ((g + i) << 4) + vq;   // lane (4(g+i)+quad), byte addr
                    unsigned bs = (unsigned)__builtin_amdgcn_ds_bpermute(bidx, (int)sp.x);
                    unsigned bp = (unsigned)__builtin_amdgcn_ds_bpermute(bidx, (int)sp.y);
                    pw[i] = __uint_as_float(bp);
                    uu[i] = h2q[bs * 16u + (unsigned)ql];
                }
#pragma unroll
                for (int i = 0; i < 4; ++i) {
                    float2 f0 = bf2f(uu[i].x), f1 = bf2f(uu[i].y);
                    float2 f2 = bf2f(uu[i].z), f3 = bf2f(uu[i].w);
                    float p = pw[i];
                    a[0] = fmaf(p, f0.x, a[0]); a[1] = fmaf(p, f0.y, a[1]);
                    a[2] = fmaf(p, f1.x, a[2]); a[3] = fmaf(p, f1.y, a[3]);
                    a[4] = fmaf(p, f2.x, a[4]); a[5] = fmaf(p, f2.y, a[5]);
                    a[6] = fmaf(p, f3.x, a[6]); a[7] = fmaf(p, f3.y, a[7]);
                    pws += p;
                }
            }
        }
        // cross-quad reduce: lanes {ql, ql+16, ql+32, ql+48} hold the 4 partials
#pragma unroll
        for (int k = 0; k < 8; ++k) {
            a[k] += __shfl_xor(a[k], 16);
            a[k] += __shfl_xor(a[k], 32);
        }
        pws += __shfl_xor(pws, 16);
        pws += __shfl_xor(pws, 32);
        float inv = 1.0f / (psf + pws);
        float o[8];
#pragma unroll
        for (int k = 0; k < 8; ++k) o[k] = fmaxf(fmaf(a[k], inv, bl[k]), 0.f);
        // lane pools features ql*8 + 2*quad {,+1}; static selects (no scratch array)
        float s0 = quad == 0 ? o[0] : quad == 1 ? o[2] : quad == 2 ? o[4] : o[6];
        float s1 = quad == 0 ? o[1] : quad == 1 ? o[3] : quad == 2 ? o[5] : o[7];
        int g = batch[n];
        if (g != gcur) {
            if (gcur >= 0) {
                unsigned* outp = (unsigned*)(out + (size_t)gcur * HID);
                atomicMax(&outp[ql * 8 + 2 * quad],     __float_as_uint(m0));
                atomicMax(&outp[ql * 8 + 2 * quad + 1], __float_as_uint(m1));
            }
            gcur = g; m0 = s0; m1 = s1;
        } else {
            m0 = fmaxf(m0, s0); m1 = fmaxf(m1, s1);
        }
    }
    if (gcur >= 0) {
        unsigned* outp = (unsigned*)(out + (size_t)gcur * HID);
        atomicMax(&outp[ql * 8 + 2 * quad],     __float_as_uint(m0));
        atomicMax(&outp[ql * 8 + 2 * quad + 1], __float_as_uint(m1));
    }
}

// ---------------------------------------------------------------- launch
extern "C" void kernel_launch(void* const* d_in, const int* in_sizes, int n_in,
                              void* d_out, int out_size, void* d_ws, size_t ws_size,
                              hipStream_t stream) {
    const float* x     = (const float*)d_in[0];
    const float* W     = (const float*)d_in[1];
    const float* att_s = (const float*)d_in[2];
    const float* att_d = (const float*)d_in[3];
    const float* bias  = (const float*)d_in[4];
    const int*   ei    = (const int*)d_in[5];
    const int*   batch = (const int*)d_in[6];
    float*       out   = (float*)d_out;

    char* ws = (char*)d_ws;
    size_t off = 0;
    auto alloc = [&](size_t bytes) -> void* {
        void* p = ws + off;
        off += (bytes + 255) & ~(size_t)255;
        return p;
    };
    const int NB = (N_NODES + 1023) / 1024;   // 49
    __bf16* h2       = (__bf16*)alloc((size_t)N_NODES * HID * 2);
    __bf16* wt       = (__bf16*)alloc((size_t)HID * IN_DIM * 2);
    float*  a_src    = (float*)alloc((size_t)N_NODES * 4);
    float*  a_dst    = (float*)alloc((size_t)N_NODES * 4);
    float*  pself    = (float*)alloc((size_t)N_NODES * 4);
    int*    deg      = (int*)alloc((size_t)N_NODES * 4);
    int*    rowstart = (int*)alloc((size_t)(N_NODES + 1) * 4);
    int*    cursor   = (int*)alloc((size_t)N_NODES * 4);
    int*    bsum     = (int*)alloc((size_t)NB * 4);
    int*    boff     = (int*)alloc((size_t)NB * 4);
    uint2*  csrp     = (uint2*)alloc((size_t)N_EDGES * 8);
    (void)ws_size; (void)in_sizes; (void)n_in;

    hipLaunchKernelGGL(prep_kernel, dim3(512), dim3(256), 0, stream,
                       W, wt, deg, out, out_size);
    hipLaunchKernelGGL(gemm_kernel, dim3((N_NODES + 63) / 64), dim3(256), 0, stream,
                       x, wt, h2, att_s, att_d, a_src, a_dst, pself);
    hipLaunchKernelGGL(hist_kernel, dim3((N_EDGES + 255) / 256), dim3(256), 0, stream,
                       ei, deg);
    hipLaunchKernelGGL(scan1_kernel, dim3(NB), dim3(256), 0, stream, deg, bsum);
    hipLaunchKernelGGL(scan2_kernel, dim3(1), dim3(64), 0, stream, bsum, boff, rowstart, NB);
    hipLaunchKernelGGL(scan3_kernel, dim3(NB), dim3(256), 0, stream, deg, boff, rowstart, cursor);
    hipLaunchKernelGGL(scatter_kernel, dim3((N_EDGES + 255) / 256), dim3(256), 0, stream,
                       ei, cursor, csrp, a_src, a_dst);
    hipLaunchKernelGGL(aggregate_kernel, dim3(AGG_WAVES / 4), dim3(256), 0, stream,
                       (const uint4*)h2, pself, rowstart, csrp, bias, batch, out);
}